// Round 3
// baseline (290.336 us; speedup 1.0000x reference)
//
#include <hip/hip_runtime.h>
#include <math.h>

#define NBINS 15
#define BLK 256

typedef float v4f __attribute__((ext_vector_type(4)));

// Process one v4f's 4 components into accumulator set k.
#define PROC4(v, k)                                                              \
    do {                                                                         \
        float f;                                                                 \
        f = (v).x; if (f > m##k) { s##k *= __expf(m##k - f); m##k = f; }         \
        s##k += __expf(f - m##k); if (f < xt) m2##k = fmaxf(m2##k, f);           \
        f = (v).y; if (f > m##k) { s##k *= __expf(m##k - f); m##k = f; }         \
        s##k += __expf(f - m##k); if (f < xt) m2##k = fmaxf(m2##k, f);           \
        f = (v).z; if (f > m##k) { s##k *= __expf(m##k - f); m##k = f; }         \
        s##k += __expf(f - m##k); if (f < xt) m2##k = fmaxf(m2##k, f);           \
        f = (v).w; if (f > m##k) { s##k *= __expf(m##k - f); m##k = f; }         \
        s##k += __expf(f - m##k); if (f < xt) m2##k = fmaxf(m2##k, f);           \
    } while (0)

// One block per row. Single streaming pass computing:
//   m  = row max
//   s  = sum exp(x - m)   (online rescale)
//   m2 = max{ x_i : x_i < x_t }   (logit-space equivalent of probs < p_k)
// Last block to finish performs the deterministic final sum.
__global__ __launch_bounds__(BLK) void row_loss_kernel(
    const float* __restrict__ inp,
    const int* __restrict__ target,
    const float* __restrict__ uppers,
    const float* __restrict__ gammas,
    float* __restrict__ row_loss,
    unsigned int* __restrict__ counter,
    float* __restrict__ out,
    int C, int N)
{
    const int row = blockIdx.x;
    const float* __restrict__ x = inp + (size_t)row * (size_t)C;
    const float xt = x[target[row]];   // broadcast load

    float m0 = -INFINITY, s0 = 0.0f, m20 = -INFINITY;
    float m1 = -INFINITY, s1 = 0.0f, m21 = -INFINITY;

    const int nvec = C >> 2;
    const v4f* __restrict__ xv = (const v4f*)x;

    int i = threadIdx.x;
    for (; i + BLK < nvec; i += 2 * BLK) {
        v4f a = __builtin_nontemporal_load(&xv[i]);
        v4f b = __builtin_nontemporal_load(&xv[i + BLK]);
        PROC4(a, 0);
        PROC4(b, 1);
    }
    if (i < nvec) {
        v4f a = __builtin_nontemporal_load(&xv[i]);
        PROC4(a, 0);
    }
    // scalar tail (C % 4 != 0 safety; C=32000 -> no-op)
    for (int j = (nvec << 2) + threadIdx.x; j < C; j += BLK) {
        float f = x[j];
        if (f > m0) { s0 *= __expf(m0 - f); m0 = f; }
        s0 += __expf(f - m0);
        if (f < xt) m20 = fmaxf(m20, f);
    }

    // merge accumulator set 1 into 0
    {
        float M = fmaxf(m0, m1);
        s0 = s0 * __expf(m0 - M) + s1 * __expf(m1 - M);
        m0 = M;
        m20 = fmaxf(m20, m21);
    }

    // wave-64 butterfly reduce
    #pragma unroll
    for (int off = 32; off > 0; off >>= 1) {
        float om  = __shfl_xor(m0,  off);
        float os  = __shfl_xor(s0,  off);
        float om2 = __shfl_xor(m20, off);
        float M = fmaxf(m0, om);
        s0 = s0 * __expf(m0 - M) + os * __expf(om - M);
        m0 = M;
        m20 = fmaxf(m20, om2);
    }

    __shared__ float sm[4], ss[4], sm2[4];
    __shared__ bool amLast;
    const int wid  = threadIdx.x >> 6;
    const int lane = threadIdx.x & 63;
    if (lane == 0) { sm[wid] = m0; ss[wid] = s0; sm2[wid] = m20; }
    __syncthreads();

    if (threadIdx.x == 0) {
        float m = sm[0], s = ss[0], m2 = sm2[0];
        #pragma unroll
        for (int w = 1; w < 4; ++w) {
            float M = fmaxf(m, sm[w]);
            s = s * __expf(m - M) + ss[w] * __expf(sm[w] - M);
            m = M;
            m2 = fmaxf(m2, sm2[w]);
        }
        const float logZ  = m + __logf(s);
        const float logpk = xt - logZ;
        const float pk    = __expf(logpk);
        const float pj    = (m2 == -INFINITY) ? 0.0f : __expf(m2 - logZ);
        const float pt    = pk - pj;

        int idx = 0;
        #pragma unroll
        for (int j = 0; j < NBINS; ++j) idx += (uppers[j] <= pt) ? 1 : 0;
        if (idx > NBINS - 1) idx = NBINS - 1;

        const float gamma = gammas[idx];
        const float base  = 1.0f - pk + pj;
        row_loss[row] = -__powf(base, gamma) * logpk;

        __threadfence();                         // release row_loss write
        unsigned int t = atomicAdd(counter, 1u); // device-scope
        amLast = (t == (unsigned int)(gridDim.x - 1));
    }
    __syncthreads();

    if (amLast) {
        __threadfence();                         // acquire: see all row_loss
        float acc = 0.0f;
        for (int j = threadIdx.x; j < N; j += BLK) acc += row_loss[j];
        #pragma unroll
        for (int off = 32; off > 0; off >>= 1) acc += __shfl_xor(acc, off);
        __shared__ float sacc[4];
        if (lane == 0) sacc[wid] = acc;
        __syncthreads();
        if (threadIdx.x == 0) out[0] = sacc[0] + sacc[1] + sacc[2] + sacc[3];
    }
}

extern "C" void kernel_launch(void* const* d_in, const int* in_sizes, int n_in,
                              void* d_out, int out_size, void* d_ws, size_t ws_size,
                              hipStream_t stream) {
    const float* inp    = (const float*)d_in[0];
    const int*   target = (const int*)d_in[1];
    const float* uppers = (const float*)d_in[2];
    const float* gammas = (const float*)d_in[3];
    float* out = (float*)d_out;

    const int N = in_sizes[1];            // 4096
    const int C = in_sizes[0] / N;        // 32000

    float* row_loss = (float*)d_ws;
    const size_t counter_off = ((size_t)N * sizeof(float) + 127) & ~(size_t)127;
    unsigned int* counter = (unsigned int*)((char*)d_ws + counter_off);

    (void)hipMemsetAsync(counter, 0, sizeof(unsigned int), stream);
    row_loss_kernel<<<N, BLK, 0, stream>>>(inp, target, uppers, gammas,
                                           row_loss, counter, out, C, N);
}

// Round 5
// 105.261 us; speedup vs baseline: 2.7583x; 2.7583x over previous
//
#include <hip/hip_runtime.h>
#include <math.h>

#define NBINS 15
#define BLK 256

typedef float v4f __attribute__((ext_vector_type(4)));

// Process one v4f's 4 components into accumulator set k (k = a,b,c,d).
#define PROC4(v, k)                                                              \
    do {                                                                         \
        float f;                                                                 \
        f = (v).x; if (f > m##k) { s##k *= __expf(m##k - f); m##k = f; }         \
        s##k += __expf(f - m##k); if (f < xt) m2##k = fmaxf(m2##k, f);           \
        f = (v).y; if (f > m##k) { s##k *= __expf(m##k - f); m##k = f; }         \
        s##k += __expf(f - m##k); if (f < xt) m2##k = fmaxf(m2##k, f);           \
        f = (v).z; if (f > m##k) { s##k *= __expf(m##k - f); m##k = f; }         \
        s##k += __expf(f - m##k); if (f < xt) m2##k = fmaxf(m2##k, f);           \
        f = (v).w; if (f > m##k) { s##k *= __expf(m##k - f); m##k = f; }         \
        s##k += __expf(f - m##k); if (f < xt) m2##k = fmaxf(m2##k, f);           \
    } while (0)

// One block per row. Single streaming pass computing:
//   m  = row max
//   s  = sum exp(x - m)   (online rescale)
//   m2 = max{ x_i : x_i < x_t }   (logit-space equivalent of probs < p_k)
// 4 independent accumulator sets -> 4 loads in flight per iteration.
__global__ __launch_bounds__(BLK) void row_loss_kernel(
    const float* __restrict__ inp,
    const int* __restrict__ target,
    const float* __restrict__ uppers,
    const float* __restrict__ gammas,
    float* __restrict__ row_loss,
    int C)
{
    const int row = blockIdx.x;
    const float* __restrict__ x = inp + (size_t)row * (size_t)C;
    const float xt = x[target[row]];   // broadcast load

    float ma = -INFINITY, sa = 0.0f, m2a = -INFINITY;
    float mb = -INFINITY, sb = 0.0f, m2b = -INFINITY;
    float mc = -INFINITY, sc = 0.0f, m2c = -INFINITY;
    float md = -INFINITY, sd = 0.0f, m2d = -INFINITY;

    const int nvec = C >> 2;
    const v4f* __restrict__ xv = (const v4f*)x;

    int i = threadIdx.x;
    for (; i + 3 * BLK < nvec; i += 4 * BLK) {
        v4f a = xv[i];
        v4f b = xv[i + BLK];
        v4f c = xv[i + 2 * BLK];
        v4f d = xv[i + 3 * BLK];
        PROC4(a, a);
        PROC4(b, b);
        PROC4(c, c);
        PROC4(d, d);
    }
    for (; i < nvec; i += BLK) {
        v4f a = xv[i];
        PROC4(a, a);
    }
    // scalar tail (C % 4 != 0 safety; C=32000 -> no-op)
    for (int j = (nvec << 2) + threadIdx.x; j < C; j += BLK) {
        float f = x[j];
        if (f > ma) { sa *= __expf(ma - f); ma = f; }
        sa += __expf(f - ma);
        if (f < xt) m2a = fmaxf(m2a, f);
    }

    // merge accumulator sets b,c,d into a
    {
        float M;
        M = fmaxf(ma, mb); sa = sa * __expf(ma - M) + sb * __expf(mb - M); ma = M;
        M = fmaxf(ma, mc); sa = sa * __expf(ma - M) + sc * __expf(mc - M); ma = M;
        M = fmaxf(ma, md); sa = sa * __expf(ma - M) + sd * __expf(md - M); ma = M;
        m2a = fmaxf(fmaxf(m2a, m2b), fmaxf(m2c, m2d));
    }

    // wave-64 butterfly reduce
    #pragma unroll
    for (int off = 32; off > 0; off >>= 1) {
        float om  = __shfl_xor(ma,  off);
        float os  = __shfl_xor(sa,  off);
        float om2 = __shfl_xor(m2a, off);
        float M = fmaxf(ma, om);
        sa = sa * __expf(ma - M) + os * __expf(om - M);
        ma = M;
        m2a = fmaxf(m2a, om2);
    }

    __shared__ float sm[4], ss[4], sm2[4];
    const int wid  = threadIdx.x >> 6;
    const int lane = threadIdx.x & 63;
    if (lane == 0) { sm[wid] = ma; ss[wid] = sa; sm2[wid] = m2a; }
    __syncthreads();

    if (threadIdx.x == 0) {
        float m = sm[0], s = ss[0], m2 = sm2[0];
        #pragma unroll
        for (int w = 1; w < 4; ++w) {
            float M = fmaxf(m, sm[w]);
            s = s * __expf(m - M) + ss[w] * __expf(sm[w] - M);
            m = M;
            m2 = fmaxf(m2, sm2[w]);
        }
        const float logZ  = m + __logf(s);
        const float logpk = xt - logZ;
        const float pk    = __expf(logpk);
        const float pj    = (m2 == -INFINITY) ? 0.0f : __expf(m2 - logZ);
        const float pt    = pk - pj;

        int idx = 0;
        #pragma unroll
        for (int j = 0; j < NBINS; ++j) idx += (uppers[j] <= pt) ? 1 : 0;
        if (idx > NBINS - 1) idx = NBINS - 1;

        const float gamma = gammas[idx];
        const float base  = 1.0f - pk + pj;
        row_loss[row] = -__powf(base, gamma) * logpk;
    }
}

// Deterministic final sum of N per-row losses (single block).
__global__ __launch_bounds__(BLK) void sum_kernel(
    const float* __restrict__ v, float* __restrict__ out, int n)
{
    float acc = 0.0f;
    for (int i = threadIdx.x; i < n; i += BLK) acc += v[i];
    #pragma unroll
    for (int off = 32; off > 0; off >>= 1) acc += __shfl_xor(acc, off);
    __shared__ float sacc[4];
    const int wid  = threadIdx.x >> 6;
    const int lane = threadIdx.x & 63;
    if (lane == 0) sacc[wid] = acc;
    __syncthreads();
    if (threadIdx.x == 0) out[0] = sacc[0] + sacc[1] + sacc[2] + sacc[3];
}

extern "C" void kernel_launch(void* const* d_in, const int* in_sizes, int n_in,
                              void* d_out, int out_size, void* d_ws, size_t ws_size,
                              hipStream_t stream) {
    const float* inp    = (const float*)d_in[0];
    const int*   target = (const int*)d_in[1];
    const float* uppers = (const float*)d_in[2];
    const float* gammas = (const float*)d_in[3];
    float* out = (float*)d_out;
    float* ws  = (float*)d_ws;

    const int N = in_sizes[1];            // 4096
    const int C = in_sizes[0] / N;        // 32000

    row_loss_kernel<<<N, BLK, 0, stream>>>(inp, target, uppers, gammas, ws, C);
    sum_kernel<<<1, BLK, 0, stream>>>(ws, out, N);
}